// Round 1
// baseline (414.142 us; speedup 1.0000x reference)
//
#include <hip/hip_runtime.h>
#include <stdint.h>

typedef __attribute__((ext_vector_type(8))) short bf16x8_t;   // 8 bf16 in 4 VGPRs
typedef __attribute__((ext_vector_type(4))) float f32x4_t;

#define DI __device__ __forceinline__

DI unsigned short f2b(float f) {
  union { float f; unsigned int u; } c; c.f = f;
  unsigned int u = c.u + 0x7FFFu + ((c.u >> 16) & 1u);   // RNE
  return (unsigned short)(u >> 16);
}
DI float b2f(unsigned short h) {
  union { unsigned int u; float f; } c; c.u = ((unsigned int)h) << 16;
  return c.f;
}
DI float silu_f(float z) { return z / (1.0f + __expf(-z)); }

// async global->LDS, 16B per lane; LDS dst = wave-uniform base + lane*16B
DI void load_lds16(const unsigned short* g, unsigned short* l) {
  __builtin_amdgcn_global_load_lds(
      (const __attribute__((address_space(1))) unsigned int*)g,
      (__attribute__((address_space(3))) unsigned int*)l,
      16, 0, 0);
}

// ---------------------------------------------------------------- transpose
DI float to_f(float v) { return v; }
DI float to_f(unsigned short v) { return b2f(v); }

template <typename T>
__global__ __launch_bounds__(256) void transpose_bf16(
    const T* __restrict__ in, unsigned short* __restrict__ out,
    int R, int C, long inZ, long outZ) {
  __shared__ float tile[32][33];
  const int tx = threadIdx.x, ty = threadIdx.y;
  const int c0 = blockIdx.x * 32, r0 = blockIdx.y * 32;
  in += (long)blockIdx.z * inZ;
  out += (long)blockIdx.z * outZ;
#pragma unroll
  for (int i = 0; i < 4; ++i)
    tile[ty + 8 * i][tx] = to_f(in[(long)(r0 + ty + 8 * i) * C + c0 + tx]);
  __syncthreads();
#pragma unroll
  for (int i = 0; i < 4; ++i)
    out[(long)(c0 + ty + 8 * i) * R + r0 + tx] = f2b(tile[tx][ty + 8 * i]);
}

// ---------------------------------------------------------------- layernorm
__global__ __launch_bounds__(256) void ln_kernel(
    const float* __restrict__ x, const float* __restrict__ g,
    const float* __restrict__ b, unsigned short* __restrict__ out) {
  __shared__ float red[8];
  const int row = blockIdx.x, tid = threadIdx.x;
  float4 v = ((const float4*)(x + (long)row * 1024))[tid];
  float s = v.x + v.y + v.z + v.w;
  float ss = v.x * v.x + v.y * v.y + v.z * v.z + v.w * v.w;
  for (int o = 32; o > 0; o >>= 1) { s += __shfl_down(s, o); ss += __shfl_down(ss, o); }
  const int wave = tid >> 6, lane = tid & 63;
  if (lane == 0) { red[wave * 2] = s; red[wave * 2 + 1] = ss; }
  __syncthreads();
  if (tid == 0) {
    float S = red[0] + red[2] + red[4] + red[6];
    float SS = red[1] + red[3] + red[5] + red[7];
    float mu = S * (1.0f / 1024.0f);
    float var = SS * (1.0f / 1024.0f) - mu * mu;
    red[0] = mu; red[1] = rsqrtf(var + 1e-5f);
  }
  __syncthreads();
  const float mu = red[0], rstd = red[1];
  float4 gg = ((const float4*)g)[tid];
  float4 bb = ((const float4*)b)[tid];
  ushort4 o;
  o.x = f2b((v.x - mu) * rstd * gg.x + bb.x);
  o.y = f2b((v.y - mu) * rstd * gg.y + bb.y);
  o.z = f2b((v.z - mu) * rstd * gg.z + bb.z);
  o.w = f2b((v.w - mu) * rstd * gg.w + bb.w);
  ((ushort4*)(out + (long)row * 1024))[tid] = o;
}

// ---------------------------------------------------------------- rope
// heads: 0=quad_q 1=lin_q 2=quad_k 3=lin_k ; y = qk*gamma[h]+beta[h]; rope over seq pos
__global__ __launch_bounds__(256) void rope_kernel(
    const unsigned short* __restrict__ qk, const float* __restrict__ gamma,
    const float* __restrict__ beta, unsigned short* __restrict__ qq,
    unsigned short* __restrict__ lq, unsigned short* __restrict__ qkh,
    unsigned short* __restrict__ lk) {
  const int tx = threadIdx.x;              // j in [0,64)
  const int ty = threadIdx.y;              // token within chunk
  const long t = (long)blockIdx.x * 4 + ty;
  const int pos = (int)(t & 2047);
  const float x1 = b2f(qk[t * 128 + tx]);
  const float x2 = b2f(qk[t * 128 + 64 + tx]);
  const float freq = powf(10000.0f, (float)tx * (1.0f / 64.0f));
  const float ang = (float)pos * freq;
  const float sn = sinf(ang), cs = cosf(ang);
  unsigned short* outs[4] = {qq, lq, qkh, lk};
#pragma unroll
  for (int h = 0; h < 4; ++h) {
    const float g1 = gamma[h * 128 + tx], g2 = gamma[h * 128 + 64 + tx];
    const float e1 = beta[h * 128 + tx], e2 = beta[h * 128 + 64 + tx];
    const float y1 = x1 * g1 + e1, y2 = x2 * g2 + e2;
    outs[h][t * 128 + tx] = f2b(y1 * cs - y2 * sn);
    outs[h][t * 128 + 64 + tx] = f2b(y2 * cs + y1 * sn);
  }
}

// ---------------------------------------------------------------- GEMM (BT)
enum { EPI_HSPLIT, EPI_SILU, EPI_ARELU, EPI_SCALE, EPI_STORE, EPI_QUAD, EPI_FINAL };

struct GemmP {
  const unsigned short* A;
  const unsigned short* B;
  int K, lda, ldb, ldc, mPerZ;
  long aZ, bZ;
  float scale;
  const float* bias;
  const float* xres;
  const unsigned short* Lin;
  const unsigned short* gateIn;
  unsigned short* outU;
  unsigned short* vTout;
  unsigned short* gateOut;
  float* outF;
};

template <int EPI>
__global__ __launch_bounds__(256, 2) void gemm_bt(GemmP p) {
  __shared__ unsigned short As[128 * 32];
  __shared__ unsigned short Bs[128 * 32];
  const int tid = threadIdx.x;
  const int lane = tid & 63;
  const int wave = tid >> 6;
  const int bx = blockIdx.x, by = blockIdx.y, z = blockIdx.z;

  long boff;
  if constexpr (EPI == EPI_QUAD)
    boff = (long)(z >> 3) * p.bZ + (long)(z & 7) * 256;  // vT[b] + g*256 column slice
  else
    boff = (long)z * p.bZ;

  const unsigned short* Ag = p.A + (long)z * p.aZ +
      (long)(bx * 128 + wave * 32 + (lane >> 2)) * p.lda + (lane & 3) * 8;
  const unsigned short* Bg = p.B + boff +
      (long)(by * 128 + wave * 32 + (lane >> 2)) * p.ldb + (lane & 3) * 8;
  unsigned short* lA = As + wave * 32 * 32;
  unsigned short* lB = Bs + wave * 32 * 32;

  const int wm = (wave & 1) * 64;
  const int wn = (wave >> 1) * 64;
  const int lm = lane & 15;
  const int kb = lane >> 4;

  f32x4_t acc[4][4];
#pragma unroll
  for (int i = 0; i < 4; ++i)
#pragma unroll
    for (int j = 0; j < 4; ++j) acc[i][j] = (f32x4_t){0.f, 0.f, 0.f, 0.f};

  const int ksteps = p.K >> 5;
  const int a16 = 16 * p.lda;
  const int b16 = 16 * p.ldb;
  for (int kt = 0; kt < ksteps; ++kt) {
    load_lds16(Ag, lA);
    load_lds16(Ag + a16, lA + 16 * 32);
    load_lds16(Bg, lB);
    load_lds16(Bg + b16, lB + 16 * 32);
    Ag += 32; Bg += 32;
    __syncthreads();
    bf16x8_t aF[4], bF[4];
#pragma unroll
    for (int i = 0; i < 4; ++i)
      aF[i] = *(const bf16x8_t*)(As + (wm + i * 16 + lm) * 32 + kb * 8);
#pragma unroll
    for (int j = 0; j < 4; ++j)
      bF[j] = *(const bf16x8_t*)(Bs + (wn + j * 16 + lm) * 32 + kb * 8);
#pragma unroll
    for (int i = 0; i < 4; ++i)
#pragma unroll
      for (int j = 0; j < 4; ++j)
        acc[i][j] = __builtin_amdgcn_mfma_f32_16x16x32_bf16(aF[i], bF[j], acc[i][j], 0, 0, 0);
    __syncthreads();
  }

#pragma unroll
  for (int i = 0; i < 4; ++i) {
    const int row0 = bx * 128 + wm + i * 16 + (lane >> 4) * 4;
    const long rowg0 = (long)z * p.mPerZ + row0;
#pragma unroll
    for (int j = 0; j < 4; ++j) {
      const int col = by * 128 + wn + j * 16 + lm;
      if constexpr (EPI == EPI_HSPLIT) {
        const float bb = p.bias[col];
        const float s0 = silu_f(acc[i][j][0] + bb);
        const float s1 = silu_f(acc[i][j][1] + bb);
        const float s2 = silu_f(acc[i][j][2] + bb);
        const float s3 = silu_f(acc[i][j][3] + bb);
        if (col < 2048) {  // v half -> store transposed into vT[b][e][n]
          const int bidx = row0 >> 11;
          const int nloc = row0 & 2047;
          ushort4 pk;
          pk.x = f2b(s0); pk.y = f2b(s1); pk.z = f2b(s2); pk.w = f2b(s3);
          *(ushort4*)(p.vTout + ((long)bidx * 2048 + col) * 2048 + nloc) = pk;
        } else {  // gate half -> [m][e]
          const int cg = col - 2048;
          p.gateOut[(long)(row0 + 0) * 2048 + cg] = f2b(s0);
          p.gateOut[(long)(row0 + 1) * 2048 + cg] = f2b(s1);
          p.gateOut[(long)(row0 + 2) * 2048 + cg] = f2b(s2);
          p.gateOut[(long)(row0 + 3) * 2048 + cg] = f2b(s3);
        }
      } else if constexpr (EPI == EPI_SILU) {
        const float bb = p.bias[col];
#pragma unroll
        for (int r = 0; r < 4; ++r)
          p.outU[(rowg0 + r) * (long)p.ldc + col] = f2b(silu_f(acc[i][j][r] + bb));
      } else if constexpr (EPI == EPI_ARELU) {
#pragma unroll
        for (int r = 0; r < 4; ++r) {
          float s = acc[i][j][r] * p.scale;
          s = s > 0.f ? s : 0.f;
          p.outU[(rowg0 + r) * (long)p.ldc + col] = f2b(s * s);
        }
      } else if constexpr (EPI == EPI_SCALE || EPI == EPI_STORE) {
#pragma unroll
        for (int r = 0; r < 4; ++r)
          p.outU[(rowg0 + r) * (long)p.ldc + col] = f2b(acc[i][j][r] * p.scale);
      } else if constexpr (EPI == EPI_QUAD) {
#pragma unroll
        for (int r = 0; r < 4; ++r) {
          const long idx = (rowg0 + r) * (long)p.ldc + col;
          const float o = b2f(p.gateIn[idx]) * (acc[i][j][r] + b2f(p.Lin[idx]));
          p.outU[idx] = f2b(o);
        }
      } else {  // EPI_FINAL: + b_out + x residual, fp32 out
        const float bb = p.bias[col];
#pragma unroll
        for (int r = 0; r < 4; ++r) {
          const long idx = (rowg0 + r) * (long)p.ldc + col;
          p.outF[idx] = acc[i][j][r] + bb + p.xres[idx];
        }
      }
    }
  }
}

// ---------------------------------------------------------------- launch
extern "C" void kernel_launch(void* const* d_in, const int* in_sizes, int n_in,
                              void* d_out, int out_size, void* d_ws, size_t ws_size,
                              hipStream_t stream) {
  const float* x        = (const float*)d_in[0];
  const float* ln_g     = (const float*)d_in[1];
  const float* ln_b     = (const float*)d_in[2];
  const float* W_hidden = (const float*)d_in[3];
  const float* b_hidden = (const float*)d_in[4];
  const float* W_qk     = (const float*)d_in[5];
  const float* b_qk     = (const float*)d_in[6];
  const float* os_gamma = (const float*)d_in[7];
  const float* os_beta  = (const float*)d_in[8];
  const float* W_out    = (const float*)d_in[9];
  const float* b_out    = (const float*)d_in[10];
  float* out = (float*)d_out;

  char* w = (char*)d_ws;
  auto ws = [&](size_t bytes) { char* p = w; w += bytes; return (unsigned short*)p; };
  unsigned short* WhT    = ws(8388608);   // [4096][1024] bf16
  unsigned short* WoT    = ws(4194304);   // [1024][2048]
  unsigned short* WqkT   = ws(262144);    // [128][1024]
  unsigned short* normed = ws(16777216);  // [8192][1024]
  unsigned short* vT     = ws(33554432);  // [4][2048 e][2048 n]
  unsigned short* gate   = ws(33554432);  // [8192][2048]
  unsigned short* qkb    = ws(2097152);   // [8192][128]
  unsigned short* qq     = ws(2097152);
  unsigned short* qkh    = ws(2097152);
  unsigned short* lq     = ws(2097152);
  unsigned short* lk     = ws(2097152);
  unsigned short* lkT    = ws(2097152);   // [4][128][2048]
  unsigned short* attn   = ws(4194304);   // [32][256][256]
  unsigned short* lkvT   = ws(2097152);   // [4][2048 e][128 d]
  unsigned short* L      = ws(33554432);  // [8192][2048]
  unsigned short* A3     = ws(33554432);  // [8192][2048]

  dim3 tb(32, 8);
  transpose_bf16<float><<<dim3(128, 32, 1), tb, 0, stream>>>(W_hidden, WhT, 1024, 4096, 0, 0);
  transpose_bf16<float><<<dim3(32, 64, 1), tb, 0, stream>>>(W_out, WoT, 2048, 1024, 0, 0);
  transpose_bf16<float><<<dim3(4, 32, 1), tb, 0, stream>>>(W_qk, WqkT, 1024, 128, 0, 0);
  ln_kernel<<<8192, 256, 0, stream>>>(x, ln_g, ln_b, normed);

  {  // GEMM1: h = silu(normed @ W_hidden + b) -> vT + gate
    GemmP p{}; p.A = normed; p.B = WhT; p.K = 1024; p.lda = 1024; p.ldb = 1024;
    p.ldc = 0; p.mPerZ = 0; p.aZ = 0; p.bZ = 0; p.bias = b_hidden;
    p.vTout = vT; p.gateOut = gate;
    gemm_bt<EPI_HSPLIT><<<dim3(64, 32, 1), 256, 0, stream>>>(p);
  }
  {  // qk = silu(normed @ W_qk + b)
    GemmP p{}; p.A = normed; p.B = WqkT; p.K = 1024; p.lda = 1024; p.ldb = 1024;
    p.ldc = 128; p.mPerZ = 0; p.bias = b_qk; p.outU = qkb;
    gemm_bt<EPI_SILU><<<dim3(64, 1, 1), 256, 0, stream>>>(p);
  }
  rope_kernel<<<2048, dim3(64, 4), 0, stream>>>(qkb, os_gamma, os_beta, qq, lq, qkh, lk);
  transpose_bf16<unsigned short><<<dim3(4, 64, 4), tb, 0, stream>>>(
      lk, lkT, 2048, 128, 2048 * 128, 2048 * 128);
  {  // sim -> attn = relu(sim/256)^2, per (b,g)
    GemmP p{}; p.A = qq; p.B = qkh; p.K = 128; p.lda = 128; p.ldb = 128;
    p.ldc = 256; p.mPerZ = 256; p.aZ = 32768; p.bZ = 32768;
    p.scale = 1.f / 256.f; p.outU = attn;
    gemm_bt<EPI_ARELU><<<dim3(2, 2, 32), 256, 0, stream>>>(p);
  }
  {  // lin_kvT[b][e][d] = sum_n vT[b][e][n]*lin_k[n][d] / 2048
    GemmP p{}; p.A = vT; p.B = lkT; p.K = 2048; p.lda = 2048; p.ldb = 2048;
    p.ldc = 128; p.mPerZ = 2048; p.aZ = 4194304; p.bZ = 262144;
    p.scale = 1.f / 2048.f; p.outU = lkvT;
    gemm_bt<EPI_SCALE><<<dim3(16, 1, 4), 256, 0, stream>>>(p);
  }
  {  // lin_out = lin_q @ lin_kv  -> L
    GemmP p{}; p.A = lq; p.B = lkvT; p.K = 128; p.lda = 128; p.ldb = 128;
    p.ldc = 2048; p.mPerZ = 2048; p.aZ = 262144; p.bZ = 262144;
    p.scale = 1.f; p.outU = L;
    gemm_bt<EPI_STORE><<<dim3(16, 16, 4), 256, 0, stream>>>(p);
  }
  {  // quad_out = attn @ vg ; A3 = gate * (quad_out + L)
    GemmP p{}; p.A = attn; p.B = vT; p.K = 256; p.lda = 256; p.ldb = 2048;
    p.ldc = 2048; p.mPerZ = 256; p.aZ = 65536; p.bZ = 4194304;
    p.Lin = L; p.gateIn = gate; p.outU = A3;
    gemm_bt<EPI_QUAD><<<dim3(2, 16, 32), 256, 0, stream>>>(p);
  }
  {  // out = A3 @ W_out + b_out + x
    GemmP p{}; p.A = A3; p.B = WoT; p.K = 2048; p.lda = 2048; p.ldb = 2048;
    p.ldc = 1024; p.mPerZ = 0; p.bias = b_out; p.xres = x; p.outF = out;
    gemm_bt<EPI_FINAL><<<dim3(64, 8, 1), 256, 0, stream>>>(p);
  }
}